// Round 1
// baseline (107.224 us; speedup 1.0000x reference)
//
#include <hip/hip_runtime.h>

#define DIM 128
#define NROWS 2048
#define NDP 64  // d-pairs

typedef float v2f __attribute__((ext_vector_type(2)));
typedef _Float16 h2 __attribute__((ext_vector_type(2)));

static __device__ __forceinline__ h2 u2h(unsigned u) { return __builtin_bit_cast(h2, u); }
static __device__ __forceinline__ unsigned h2u(h2 h) { return __builtin_bit_cast(unsigned, h); }

// ---------------------------------------------------------------------------
// prep: hi2T[dp][n] = half2( hi[2dp][n], hi[2dp+1][n] ),  hj2T likewise + b1.
// (unchanged from verified 105-us version)
// ---------------------------------------------------------------------------
__global__ __launch_bounds__(256) void prep_kernel(
    const float* __restrict__ z_i, const float* __restrict__ z_j,
    const float* __restrict__ W1, const float* __restrict__ b1,
    unsigned* __restrict__ hi2T, unsigned* __restrict__ hj2T) {
  __shared__ float zs[8 * DIM];  // 4 KB

  const int t = threadIdx.x;
  const int side = blockIdx.y;
  const int rowbase = blockIdx.x * 8;

  // stage 8 z rows (1024 floats), coalesced
  const float* z = (side ? z_j : z_i) + (size_t)rowbase * DIM;
  ((float4*)zs)[t] = ((const float4*)z)[t];
  __syncthreads();

  const int dp = t & 63;       // d-pair
  const int rg = t >> 6;       // row-group: rows rg*2, rg*2+1
  const float* wcol = W1 + side * (DIM * DIM) + dp * 2;
  const float* z0 = zs + (rg * 2) * DIM;
  const float* z1 = z0 + DIM;

  v2f acc0 = {0.f, 0.f}, acc1 = {0.f, 0.f};
#pragma unroll 8
  for (int k = 0; k < DIM; ++k) {
    const v2f wv = *(const v2f*)(wcol + (size_t)k * DIM);  // coalesced 8 B/lane
    const float a = z0[k], b = z1[k];                      // LDS broadcast
    acc0 = __builtin_elementwise_fma(wv, (v2f){a, a}, acc0);
    acc1 = __builtin_elementwise_fma(wv, (v2f){b, b}, acc1);
  }

  if (side) {
    const v2f bb = *(const v2f*)(b1 + dp * 2);
    acc0 += bb;
    acc1 += bb;
  }
  unsigned* dst = (side ? hj2T : hi2T) + (size_t)dp * NROWS + rowbase + rg * 2;
  dst[0] = h2u((h2){(_Float16)acc0.x, (_Float16)acc0.y});
  dst[1] = h2u((h2){(_Float16)acc1.x, (_Float16)acc1.y});
}

// ---------------------------------------------------------------------------
// score v2: tile 128(i) x 64(j), micro 8i x 4j per thread, 256 threads.
// grid (32 j-tiles, 16 i-tiles) = 512 blocks = exactly 2/CU (48.25 KB LDS).
// Per q-step (2 d's): 3 ds_read_b128 feed 32 outputs (96 pk-VALU ops) ->
// per-CU LDS cycles (16w x 3 x ~12cyc = 576) < per-SIMD VALU cycles
// (4w x 96 x 2 = 768): VALU-bound by construction, long VALU runs hide
// LDS latency. All LDS reads broadcast or 2-way (free).
// ---------------------------------------------------------------------------
__global__ __launch_bounds__(256, 4) void score_kernel(
    const unsigned* __restrict__ hi2T, const unsigned* __restrict__ hj2T,
    const float* __restrict__ W2, const float* __restrict__ b2p,
    float* __restrict__ out) {
  __shared__ unsigned his2[NDP * 128];  // 32 KB  [dp][i]
  __shared__ unsigned hjs2[NDP * 64];   // 16 KB  [dp][j]
  __shared__ unsigned w2s[NDP];         // 256 B

  const int t = threadIdx.x;
  const int ibase = blockIdx.y * 128;
  const int jbase = blockIdx.x * 64;
  const float bias = *b2p;

  // stage i-tile: 8192 uints, coalesced 512 B per 32 lanes
#pragma unroll
  for (int rep = 0; rep < 8; ++rep) {
    const int idx = rep * 256 + t;
    const int dp = idx >> 5, c = (idx & 31) * 4;
    *(uint4*)(his2 + dp * 128 + c) =
        *(const uint4*)(hi2T + (size_t)dp * NROWS + ibase + c);
  }
  // stage j-tile: 4096 uints
#pragma unroll
  for (int rep = 0; rep < 4; ++rep) {
    const int idx = rep * 256 + t;
    const int dp = idx >> 4, c = (idx & 15) * 4;
    *(uint4*)(hjs2 + dp * 64 + c) =
        *(const uint4*)(hj2T + (size_t)dp * NROWS + jbase + c);
  }
  if (t < NDP) {
    const v2f wp = *(const v2f*)(W2 + t * 2);
    w2s[t] = h2u((h2){(_Float16)wp.x, (_Float16)wp.y});
  }
  __syncthreads();  // the only barrier

  const int jx = t & 15;   // j-group: 4 j's
  const int iy = t >> 4;   // i-group: 8 i's

  float acc[8][4];
#pragma unroll
  for (int ii = 0; ii < 8; ++ii)
#pragma unroll
    for (int jj = 0; jj < 4; ++jj) acc[ii][jj] = 0.f;

  const h2 zero = {(_Float16)0.f, (_Float16)0.f};
#pragma unroll 2
  for (int dpg = 0; dpg < 16; ++dpg) {
    const uint4 w4 = *(const uint4*)(w2s + dpg * 4);  // broadcast
    const h2 wp[4] = {u2h(w4.x), u2h(w4.y), u2h(w4.z), u2h(w4.w)};
#pragma unroll
    for (int q = 0; q < 4; ++q) {
      const int dp = dpg * 4 + q;
      const uint4 hu0 = *(const uint4*)(his2 + dp * 128 + iy * 8);      // bcast x16
      const uint4 hu1 = *(const uint4*)(his2 + dp * 128 + iy * 8 + 4);  // bcast x16
      const uint4 ju = *(const uint4*)(hjs2 + dp * 64 + jx * 4);        // 2-way free
      const h2 hiv[8] = {u2h(hu0.x), u2h(hu0.y), u2h(hu0.z), u2h(hu0.w),
                         u2h(hu1.x), u2h(hu1.y), u2h(hu1.z), u2h(hu1.w)};
      const h2 hjv[4] = {u2h(ju.x), u2h(ju.y), u2h(ju.z), u2h(ju.w)};
#pragma unroll
      for (int ii = 0; ii < 8; ++ii) {
#pragma unroll
        for (int jj = 0; jj < 4; ++jj) {
          h2 s = hiv[ii] + hjv[jj];                  // v_pk_add_f16
          s = __builtin_elementwise_max(s, zero);    // v_pk_max_f16
          acc[ii][jj] = __builtin_amdgcn_fdot2(s, wp[q], acc[ii][jj], false);
        }
      }
    }
  }

#pragma unroll
  for (int ii = 0; ii < 8; ++ii) {
    const int i = ibase + iy * 8 + ii;
    float* o = out + (size_t)i * NROWS + jbase + jx * 4;
    const float4 ov = {acc[ii][0] + bias, acc[ii][1] + bias,
                       acc[ii][2] + bias, acc[ii][3] + bias};
    *(float4*)o = ov;  // 16 lanes x 16 B contiguous per row
  }
}

extern "C" void kernel_launch(void* const* d_in, const int* in_sizes, int n_in,
                              void* d_out, int out_size, void* d_ws, size_t ws_size,
                              hipStream_t stream) {
  const float* z_i = (const float*)d_in[0];
  const float* z_j = (const float*)d_in[1];
  const float* W1  = (const float*)d_in[2];
  const float* b1  = (const float*)d_in[3];
  const float* W2  = (const float*)d_in[4];
  const float* b2  = (const float*)d_in[5];
  float* out = (float*)d_out;

  unsigned* hi2T = (unsigned*)d_ws;             // [64][2048] half2 -> 512 KB
  unsigned* hj2T = hi2T + (size_t)NDP * NROWS;  // [64][2048] half2 -> 512 KB

  prep_kernel<<<dim3(256, 2), 256, 0, stream>>>(z_i, z_j, W1, b1, hi2T, hj2T);
  score_kernel<<<dim3(32, 16), 256, 0, stream>>>(hi2T, hj2T, W2, b2, out);
}

// Round 2
// 102.587 us; speedup vs baseline: 1.0452x; 1.0452x over previous
//
#include <hip/hip_runtime.h>

#define DIM 128
#define NROWS 2048
#define NDP 64  // d-pairs

typedef float v2f __attribute__((ext_vector_type(2)));
typedef _Float16 h2 __attribute__((ext_vector_type(2)));

static __device__ __forceinline__ h2 u2h(unsigned u) { return __builtin_bit_cast(h2, u); }
static __device__ __forceinline__ unsigned h2u(h2 h) { return __builtin_bit_cast(unsigned, h); }

// ---------------------------------------------------------------------------
// prep v3: hi2T[dp][n] = half2( hi[2dp][n], hi[2dp+1][n] ), hj2T + b1.
// No LDS: z rows are WAVE-UNIFORM (wave w owns rows rowbase..rowbase+3), so
// the row base goes through readfirstlane -> scalar (SMEM) z loads, zero
// LDS-pipe traffic (old version: 256 ds_read_b32/wave ~ 5 us/CU), no barrier.
// 4 rows/wave halves W1 L2 re-reads (128 MB -> 64 MB) and makes the
// transposed store a single uint4 (16 B) per thread.
// grid (128 row-tiles of 16, 2 sides) x 256 thr.
// ---------------------------------------------------------------------------
__global__ __launch_bounds__(256) void prep_kernel(
    const float* __restrict__ z_i, const float* __restrict__ z_j,
    const float* __restrict__ W1, const float* __restrict__ b1,
    unsigned* __restrict__ hi2T, unsigned* __restrict__ hj2T) {
  const int t = threadIdx.x;
  const int side = blockIdx.y;
  const int dp = t & 63;                                   // lane = d-pair
  const int w = __builtin_amdgcn_readfirstlane(t >> 6);    // wave id (uniform)
  const int rowbase = blockIdx.x * 16 + w * 4;             // SGPR row base

  const float* __restrict__ zr = (side ? z_j : z_i) + (size_t)rowbase * DIM;
  const float* __restrict__ wcol = W1 + side * (DIM * DIM) + dp * 2;

  v2f acc0 = {0.f, 0.f}, acc1 = {0.f, 0.f}, acc2 = {0.f, 0.f}, acc3 = {0.f, 0.f};
#pragma unroll 16
  for (int k = 0; k < DIM; ++k) {
    const v2f wv = *(const v2f*)(wcol + (size_t)k * DIM);  // coalesced 8 B/lane
    const float a0 = zr[k];                                // wave-uniform scalar
    const float a1 = zr[DIM + k];
    const float a2 = zr[2 * DIM + k];
    const float a3 = zr[3 * DIM + k];
    acc0 = __builtin_elementwise_fma(wv, (v2f){a0, a0}, acc0);
    acc1 = __builtin_elementwise_fma(wv, (v2f){a1, a1}, acc1);
    acc2 = __builtin_elementwise_fma(wv, (v2f){a2, a2}, acc2);
    acc3 = __builtin_elementwise_fma(wv, (v2f){a3, a3}, acc3);
  }

  if (side) {
    const v2f bb = *(const v2f*)(b1 + dp * 2);
    acc0 += bb;
    acc1 += bb;
    acc2 += bb;
    acc3 += bb;
  }
  unsigned* dst = (side ? hj2T : hi2T) + (size_t)dp * NROWS + rowbase;
  uint4 o;
  o.x = h2u((h2){(_Float16)acc0.x, (_Float16)acc0.y});
  o.y = h2u((h2){(_Float16)acc1.x, (_Float16)acc1.y});
  o.z = h2u((h2){(_Float16)acc2.x, (_Float16)acc2.y});
  o.w = h2u((h2){(_Float16)acc3.x, (_Float16)acc3.y});
  *(uint4*)dst = o;  // 4 consecutive rows, one 16 B store per thread
}

// ---------------------------------------------------------------------------
// score v2 (unchanged): tile 128(i) x 64(j), micro 8i x 4j per thread.
// grid (32 j-tiles, 16 i-tiles) = 512 blocks = 2/CU (48.25 KB LDS).
// Per q-step: 3 ds_read_b128 feed 32 outputs (96 pk-VALU ops); VALU-bound,
// floor ~10.2 us. All LDS reads broadcast or 2-way (free).
// ---------------------------------------------------------------------------
__global__ __launch_bounds__(256, 4) void score_kernel(
    const unsigned* __restrict__ hi2T, const unsigned* __restrict__ hj2T,
    const float* __restrict__ W2, const float* __restrict__ b2p,
    float* __restrict__ out) {
  __shared__ unsigned his2[NDP * 128];  // 32 KB  [dp][i]
  __shared__ unsigned hjs2[NDP * 64];   // 16 KB  [dp][j]
  __shared__ unsigned w2s[NDP];         // 256 B

  const int t = threadIdx.x;
  const int ibase = blockIdx.y * 128;
  const int jbase = blockIdx.x * 64;
  const float bias = *b2p;

  // stage i-tile: 8192 uints, coalesced 512 B per 32 lanes
#pragma unroll
  for (int rep = 0; rep < 8; ++rep) {
    const int idx = rep * 256 + t;
    const int dp = idx >> 5, c = (idx & 31) * 4;
    *(uint4*)(his2 + dp * 128 + c) =
        *(const uint4*)(hi2T + (size_t)dp * NROWS + ibase + c);
  }
  // stage j-tile: 4096 uints
#pragma unroll
  for (int rep = 0; rep < 4; ++rep) {
    const int idx = rep * 256 + t;
    const int dp = idx >> 4, c = (idx & 15) * 4;
    *(uint4*)(hjs2 + dp * 64 + c) =
        *(const uint4*)(hj2T + (size_t)dp * NROWS + jbase + c);
  }
  if (t < NDP) {
    const v2f wp = *(const v2f*)(W2 + t * 2);
    w2s[t] = h2u((h2){(_Float16)wp.x, (_Float16)wp.y});
  }
  __syncthreads();  // the only barrier

  const int jx = t & 15;   // j-group: 4 j's
  const int iy = t >> 4;   // i-group: 8 i's

  float acc[8][4];
#pragma unroll
  for (int ii = 0; ii < 8; ++ii)
#pragma unroll
    for (int jj = 0; jj < 4; ++jj) acc[ii][jj] = 0.f;

  const h2 zero = {(_Float16)0.f, (_Float16)0.f};
#pragma unroll 2
  for (int dpg = 0; dpg < 16; ++dpg) {
    const uint4 w4 = *(const uint4*)(w2s + dpg * 4);  // broadcast
    const h2 wp[4] = {u2h(w4.x), u2h(w4.y), u2h(w4.z), u2h(w4.w)};
#pragma unroll
    for (int q = 0; q < 4; ++q) {
      const int dp = dpg * 4 + q;
      const uint4 hu0 = *(const uint4*)(his2 + dp * 128 + iy * 8);      // bcast x16
      const uint4 hu1 = *(const uint4*)(his2 + dp * 128 + iy * 8 + 4);  // bcast x16
      const uint4 ju = *(const uint4*)(hjs2 + dp * 64 + jx * 4);        // 2-way free
      const h2 hiv[8] = {u2h(hu0.x), u2h(hu0.y), u2h(hu0.z), u2h(hu0.w),
                         u2h(hu1.x), u2h(hu1.y), u2h(hu1.z), u2h(hu1.w)};
      const h2 hjv[4] = {u2h(ju.x), u2h(ju.y), u2h(ju.z), u2h(ju.w)};
#pragma unroll
      for (int ii = 0; ii < 8; ++ii) {
#pragma unroll
        for (int jj = 0; jj < 4; ++jj) {
          h2 s = hiv[ii] + hjv[jj];                  // v_pk_add_f16
          s = __builtin_elementwise_max(s, zero);    // v_pk_max_f16
          acc[ii][jj] = __builtin_amdgcn_fdot2(s, wp[q], acc[ii][jj], false);
        }
      }
    }
  }

#pragma unroll
  for (int ii = 0; ii < 8; ++ii) {
    const int i = ibase + iy * 8 + ii;
    float* o = out + (size_t)i * NROWS + jbase + jx * 4;
    const float4 ov = {acc[ii][0] + bias, acc[ii][1] + bias,
                       acc[ii][2] + bias, acc[ii][3] + bias};
    *(float4*)o = ov;  // 16 lanes x 16 B contiguous per row
  }
}

extern "C" void kernel_launch(void* const* d_in, const int* in_sizes, int n_in,
                              void* d_out, int out_size, void* d_ws, size_t ws_size,
                              hipStream_t stream) {
  const float* z_i = (const float*)d_in[0];
  const float* z_j = (const float*)d_in[1];
  const float* W1  = (const float*)d_in[2];
  const float* b1  = (const float*)d_in[3];
  const float* W2  = (const float*)d_in[4];
  const float* b2  = (const float*)d_in[5];
  float* out = (float*)d_out;

  unsigned* hi2T = (unsigned*)d_ws;             // [64][2048] half2 -> 512 KB
  unsigned* hj2T = hi2T + (size_t)NDP * NROWS;  // [64][2048] half2 -> 512 KB

  prep_kernel<<<dim3(128, 2), 256, 0, stream>>>(z_i, z_j, W1, b1, hi2T, hj2T);
  score_kernel<<<dim3(32, 16), 256, 0, stream>>>(hi2T, hj2T, W2, b2, out);
}